// Round 9
// baseline (266.808 us; speedup 1.0000x reference)
//
#include <hip/hip_runtime.h>

// ARIMA flow sampling, R22 = R21 fixed: branch-free own-kb via ROTATED frags.
// R21 post-mortem: NaN fail. Suspect: `if (kb==wv) continue` around MFMA --
// w=tid>>6 is VGPR so compiler predicates via exec, but MFMA IGNORES EXEC on
// CDNA and the masked ds_read's dest reg is undefined -> MFMA eats garbage
// bf16 -> NaN. Fix: zero control flow. Frag arrays loaded ROTATED:
// a2r[t][j] / amr[t][j] = frag for kb=(w+j)&3 (dest index compile-time,
// rule #20 safe). Loop: gemm_own(slot 0, pre-barrier, own regs) +
// straight-line gemm_rest3(slots 1..3) with precomputed LDS offsets
// o_j = rbase + ((w+j)&3)*32. Identical instruction stream in all waves.
// Keeps both R21 cuts: (1) C-fold (C=2log2e into W1/W2/Mt/sv, tanh drops
// v_mul), (2) own-kb (skip 1 of 4 ds_read + run own kb pre-barrier).
// Predicted: pass, absmax 0.008-0.023 (kb-order f32 resum + C requant,
// thr 0.033), main 186 -> 172-178us, BANK_CONFLICT 1.32e7 -> ~1.0e7,
// VALUBusy ~55. Fail again => drop own-kb, C-fold only next.
//
// Algebra (z carried C-scaled: z_c = C*z):
//   z_c0 := (C*W1)'[x0,0,1] ; v_c = C*sv - dt*z_c0 ; h = 1-2/(e^zc+1)
//   h2 = tanh_c(C*W2'[h1,1])            (GEMM 1, W2 pre-scaled)
//   z_c += (C*dtM) @ h2 + v_c           (GEMM 2, acc_in = z_c)
//   x_100 = W3'[dt*sum_s h2_s, 1]       (unscaled)
// pi storage: position p = 32w + 8q + 4t + r holds feature
// f(p) = 32*(p>>5) + 16*((p>>2)&1) + 4*((p>>3)&3) + (p&3).

#define NB 1024
#define NQ 96
#define NC 16
#define NH 100
#define QP1 97
#define QP2 98
#define NTHR 256
#define STR 136
#define NSTEPS_ 100
#define MT_K 128  // dtM row stride (bf16)
#define CC 2.885390081777927f  // 2*log2(e)

typedef __attribute__((ext_vector_type(8))) short bf16x8;
typedef __attribute__((ext_vector_type(4))) short shortx4;
typedef __attribute__((ext_vector_type(4))) float f32x4;
typedef __attribute__((ext_vector_type(2))) float f32x2;
typedef __attribute__((ext_vector_type(4))) unsigned uintx4;

#define LO2(v) __builtin_shufflevector(v, v, 0, 1)
#define HI2(v) __builtin_shufflevector(v, v, 2, 3)

__device__ __forceinline__ f32x4 splat4(float f) {
  f32x4 v = f;
  return v;
}

__device__ __forceinline__ f32x2 splat2(float f) {
  f32x2 v = f;
  return v;
}

__device__ __forceinline__ short f2bf_rne(float f) {  // one-time paths only
  unsigned u = __builtin_bit_cast(unsigned, f);
  u = u + 0x7fffu + ((u >> 16) & 1u);
  return (short)(u >> 16);
}

// 2 floats -> packed bf16x2 dword, RNE, single instruction.
__device__ __forceinline__ unsigned cvtpk_bf16(float a, float b) {
  unsigned r;
  asm("v_cvt_pk_bf16_f32 %0, %1, %2" : "=v"(r) : "v"(a), "v"(b));
  return r;
}

// hardware exp2 (v_exp_f32)
#if __has_builtin(__builtin_amdgcn_exp2f)
__device__ __forceinline__ float hexp2(float x) {
  return __builtin_amdgcn_exp2f(x);
}
#else
__device__ __forceinline__ float hexp2(float x) {
  float r;
  asm("v_exp_f32 %0, %1\n\ts_nop 1" : "=v"(r) : "v"(x));
  return r;
}
#endif

// tanh on C-prescaled input: x = C*z -> tanh(z) = 1 - 2*rcp(exp2(x)+1).
// 2 VALU + 2 TRANS; in [-1,1] by construction, exact +-1 saturation.
__device__ __forceinline__ float tanh1c(float x) {
  float t = hexp2(x);
  float r = __builtin_amdgcn_rcpf(t + 1.0f);
  return fmaf(-2.0f, r, 1.0f);
}

__device__ __forceinline__ void tanh_pair(f32x2& p, f32x2& q) {
  p[0] = tanh1c(p[0]);
  p[1] = tanh1c(p[1]);
  q[0] = tanh1c(q[0]);
  q[1] = tanh1c(q[1]);
}

// ---------------- prep: dtM = C * dt * W1x @ W3 (bf16) + s-vec -----------
// grid 128 (= n), block 512 (k = tid&127, jslice = tid>>7); LDS reduce.
// Mt and sv carry the C scale (z-domain is C-scaled in main).
__global__ void __launch_bounds__(512) arima_prep(
    const float* __restrict__ W1, const float* __restrict__ b1,
    const float* __restrict__ W3, const float* __restrict__ b3,
    short* __restrict__ Mt, float* __restrict__ sv) {
  __shared__ float part[4][128];
  __shared__ float pb[128];
  const int n = blockIdx.x;
  const int tid = threadIdx.x;
  const int k = tid & 127, js = tid >> 7;
  float s = 0.0f;
  if (n < NH && k < NH) {
    int j0 = js * 25, j1 = (js == 3) ? QP1 : j0 + 25;
    for (int j = j0; j < j1; ++j)
      s = fmaf(W1[n * QP2 + j], W3[j * NH + k], s);
  }
  part[js][k] = s;
  if (tid < 128)
    pb[tid] = (tid < QP1 && n < NH) ? W1[n * QP2 + tid] * b3[tid] : 0.0f;
  __syncthreads();
  if (js == 0) {
    float tot = part[0][k] + part[1][k] + part[2][k] + part[3][k];
    Mt[n * MT_K + k] = f2bf_rne(0.01f * CC * tot);
  }
  if (tid == 0) {
    float d = 0.0f;
    for (int j = 0; j < 128; ++j) d += pb[j];
    sv[n] = (n < NH) ? 0.01f * CC * (d + b1[n] + W1[n * QP2 + QP1]) : 0.0f;
  }
}

// ---------------- main ----------------
// Weight A-frag from fp32 W, pi-permuted k columns, scaled:
// frag slot (kb,i) holds scale*W[m][kcol], kcol = kb*32+16*(i>>2)+quad*4+(i&3).
// kb may be a runtime value (rotation) — only addresses depend on it.
__device__ bf16x8 load_afrag_one(const float* __restrict__ W,
                                 const float* __restrict__ bias, int ws,
                                 int mvalid, int KW, int m, int quad, int kb,
                                 float scale) {
  bf16x8 v;
#pragma unroll
  for (int i = 0; i < 8; ++i) {
    int kcol = kb * 32 + ((i >> 2) << 4) + quad * 4 + (i & 3);
    float f = 0.0f;
    if (m < mvalid) {
      if (kcol < KW) f = W[m * ws + kcol];
      else if (kcol == KW) f = bias[m];
    }
    v[i] = f2bf_rne(f * scale);
  }
  return v;
}

__device__ void load_afrag(const float* __restrict__ W,
                           const float* __restrict__ bias, int ws, int mvalid,
                           int KW, int m, int quad, float scale,
                           bf16x8 dst[4]) {
#pragma unroll
  for (int kb = 0; kb < 4; ++kb)
    dst[kb] = load_afrag_one(W, bias, ws, mvalid, KW, m, quad, kb, scale);
}

// gather one pi-permuted dtM frag for (runtime) kb.
__device__ __forceinline__ bf16x8 mt_frag(const short* __restrict__ mrow,
                                          int quad, int kb) {
  shortx4 lo = *(const shortx4*)(mrow + kb * 32 + quad * 4);
  shortx4 hi = *(const shortx4*)(mrow + kb * 32 + 16 + quad * 4);
  bf16x8 vv;
  vv[0] = lo[0]; vv[1] = lo[1]; vv[2] = lo[2]; vv[3] = lo[3];
  vv[4] = hi[0]; vv[5] = hi[1]; vv[6] = hi[2]; vv[7] = hi[3];
  return vv;
}

// acc += A * B(LDS), all 4 kb, normal order (init / epilogue paths).
__device__ __forceinline__ void gemm_acc(const short* __restrict__ src,
                                         int rbase, const bf16x8 (&A)[2][4],
                                         f32x4 (&acc)[2]) {
#pragma unroll
  for (int kb = 0; kb < 4; ++kb) {
    bf16x8 bv = *(const bf16x8*)(src + rbase + kb * 32);  // 16B aligned
    acc[0] = __builtin_amdgcn_mfma_f32_16x16x32_bf16(A[0][kb], bv, acc[0], 0, 0, 0);
    acc[1] = __builtin_amdgcn_mfma_f32_16x16x32_bf16(A[1][kb], bv, acc[1], 0, 0, 0);
  }
}

// acc += A * B(LDS) over rotated slots 1..3 (slot 0 = own kb, pre-barrier).
// Straight-line: identical instruction stream in every wave, no branches.
__device__ __forceinline__ void gemm_rest3(const short* __restrict__ src,
                                           int o1, int o2, int o3,
                                           const bf16x8 (&A)[2][4],
                                           f32x4 (&acc)[2]) {
  bf16x8 b1v = *(const bf16x8*)(src + o1);
  acc[0] = __builtin_amdgcn_mfma_f32_16x16x32_bf16(A[0][1], b1v, acc[0], 0, 0, 0);
  acc[1] = __builtin_amdgcn_mfma_f32_16x16x32_bf16(A[1][1], b1v, acc[1], 0, 0, 0);
  bf16x8 b2v = *(const bf16x8*)(src + o2);
  acc[0] = __builtin_amdgcn_mfma_f32_16x16x32_bf16(A[0][2], b2v, acc[0], 0, 0, 0);
  acc[1] = __builtin_amdgcn_mfma_f32_16x16x32_bf16(A[1][2], b2v, acc[1], 0, 0, 0);
  bf16x8 b3v = *(const bf16x8*)(src + o3);
  acc[0] = __builtin_amdgcn_mfma_f32_16x16x32_bf16(A[0][3], b3v, acc[0], 0, 0, 0);
  acc[1] = __builtin_amdgcn_mfma_f32_16x16x32_bf16(A[1][3], b3v, acc[1], 0, 0, 0);
}

// own-kb MFMAs from the lane's own packed write value (no LDS, no barrier).
__device__ __forceinline__ void gemm_own(const bf16x8& A0, const bf16x8& A1,
                                         uintx4 u, f32x4 (&acc)[2]) {
  bf16x8 bv = __builtin_bit_cast(bf16x8, u);
  acc[0] = __builtin_amdgcn_mfma_f32_16x16x32_bf16(A0, bv, acc[0], 0, 0, 0);
  acc[1] = __builtin_amdgcn_mfma_f32_16x16x32_bf16(A1, bv, acc[1], 0, 0, 0);
}

// cvt_pk + ONE b128 store; returns the packed value (= own kb B-frag).
__device__ __forceinline__ uintx4 write_tile(short* __restrict__ dst, int wrow,
                                             int T0, int quad, f32x2 a0,
                                             f32x2 a1, f32x2 b0, f32x2 b1) {
  uintx4 u;
  u.x = cvtpk_bf16(a0[0], a0[1]);
  u.y = cvtpk_bf16(a1[0], a1[1]);
  u.z = cvtpk_bf16(b0[0], b0[1]);
  u.w = cvtpk_bf16(b1[0], b1[1]);
  *(uintx4*)(dst + wrow + (T0 >> 1) * 32 + quad * 8) = u;
  return u;
}

__global__ void __launch_bounds__(NTHR, 4)
arima_r22(const float* __restrict__ series,
          const float* __restrict__ rand_error, const float* __restrict__ W1,
          const float* __restrict__ b1, const float* __restrict__ W2,
          const float* __restrict__ b2, const float* __restrict__ W3,
          const float* __restrict__ b3, const short* __restrict__ Mt,
          const float* __restrict__ sv, float* __restrict__ out) {
  __shared__ __align__(16) short buf1[16 * STR];  // h1 (feat 100 = 1.0)
  __shared__ __align__(16) short buf2[16 * STR];  // x0 / h2 / H2avg

  const int tid = threadIdx.x;
  const int w = tid >> 6, l = tid & 63;
  const int col = l & 15, quad = l >> 4;  // col = channel = data row
  const int b = blockIdx.x;               // WG = one batch
  const int T0 = 2 * w;                   // uniform: wave owns tiles 2w,2w+1
  const int wrow = col * STR;
  const int rbase = wrow + quad * 8;
  const bool fixw = (w == 3 && quad == 1);  // owns feat 100 (storage 104)
  // rotated LDS offsets for slots 1..3 (slot j <-> kb=(w+j)&3)
  const int o1 = rbase + ((w + 1) & 3) * 32;
  const int o2 = rbase + ((w + 2) & 3) * 32;
  const int o3 = rbase + ((w + 3) & 3) * 32;

  // ---- x0 -> buf2 : feats [x0(97), t0=0, 1, 0...], pi-stored ----
  {
    f32x4 xv[2];
#pragma unroll
    for (int t = 0; t < 2; ++t)
#pragma unroll
      for (int r = 0; r < 4; ++r) {
        int q = (T0 + t) * 16 + quad * 4 + r;
        float f = 0.0f;
        if (q < NQ) f = series[(b * NQ + q) * NC + col];
        else if (q == NQ) f = rand_error[b * NC + col];
        else if (q == QP2) f = 1.0f;  // bias feature (q==97: t0 = 0)
        xv[t][r] = f;
      }
    write_tile(buf2, wrow, T0, quad, LO2(xv[0]), HI2(xv[0]), LO2(xv[1]),
               HI2(xv[1]));
  }

  // ---- persistent frags, ROTATED: slot j = kb=(w+j)&3 (global, no LDS dep)
  bf16x8 a2r[2][4], amr[2][4];
#pragma unroll
  for (int t = 0; t < 2; ++t) {
    const int m = (T0 + t) * 16 + col;
    const short* mrow = Mt + m * MT_K;
#pragma unroll
    for (int j = 0; j < 4; ++j) {  // dest index compile-time (rule #20)
      const int kbv = (w + j) & 3;
      a2r[t][j] = load_afrag_one(W2, b2, NH, NH, NH, m, quad, kbv, CC);
      amr[t][j] = mt_frag(mrow, quad, kbv);
    }
  }
  __syncthreads();

  // ---- z_c0 = (C*W1)'[x0,0,1] ; v_c = C*sv - dt*z_c0 ; h1_0 -> buf1 ----
  f32x4 z[2], v[2];
  {
    bf16x8 a1[2][4];  // transient, normal kb order
#pragma unroll
    for (int t = 0; t < 2; ++t)
      load_afrag(W1, b1, QP2, NH, QP2, (T0 + t) * 16 + col, quad, CC, a1[t]);
    z[0] = splat4(0.0f);
    z[1] = splat4(0.0f);
    gemm_acc(buf2, rbase, a1, z);
#pragma unroll
    for (int t = 0; t < 2; ++t) {
      f32x4 s;
#pragma unroll
      for (int r = 0; r < 4; ++r) s[r] = sv[(T0 + t) * 16 + quad * 4 + r];
      v[t] = s - splat4(0.01f) * z[t];
    }
  }
  f32x4 acc[2];  // GEMM1 accumulator; own-kb part computed pre-barrier
  {
    f32x2 p0 = LO2(z[0]), p1 = HI2(z[0]), p2 = LO2(z[1]), p3 = HI2(z[1]);
    tanh_pair(p0, p1);
    tanh_pair(p2, p3);
    if (fixw) p0[0] = 1.0f;  // h1 feat 100 = 1.0 (W2 bias input)
    uintx4 hu1 = write_tile(buf1, wrow, T0, quad, p0, p1, p2, p3);
    acc[0] = splat4(0.0f);
    acc[1] = splat4(0.0f);
    gemm_own(a2r[0][0], a2r[1][0], hu1, acc);  // pre-barrier, own regs only
  }
  __syncthreads();

  f32x2 h2s[2][2];
  h2s[0][0] = splat2(0.0f);
  h2s[0][1] = splat2(0.0f);
  h2s[1][0] = splat2(0.0f);
  h2s[1][1] = splat2(0.0f);

#pragma unroll 1
  for (int step = 0; step < NSTEPS_; ++step) {
    // GEMM 1 rest (slots 1..3): h2 = tanh_c; store; accumulate; own-kb G2.
    gemm_rest3(buf1, o1, o2, o3, a2r, acc);
    {
      f32x2 p0 = LO2(acc[0]), p1 = HI2(acc[0]), p2 = LO2(acc[1]),
            p3 = HI2(acc[1]);
      tanh_pair(p0, p1);
      tanh_pair(p2, p3);
      uintx4 hu2 = write_tile(buf2, wrow, T0, quad, p0, p1, p2, p3);
      h2s[0][0] = h2s[0][0] + p0;
      h2s[0][1] = h2s[0][1] + p1;
      h2s[1][0] = h2s[1][0] + p2;
      h2s[1][1] = h2s[1][1] + p3;
      gemm_own(amr[0][0], amr[1][0], hu2, z);  // GEMM2 own-kb, pre-barrier
    }
    __syncthreads();
    // GEMM 2 rest: z_c += (C dtM) h2 (slots 1..3), z_c += v_c ; h1' -> buf1
    gemm_rest3(buf2, o1, o2, o3, amr, z);
    {
      z[0] = z[0] + v[0];
      z[1] = z[1] + v[1];
      f32x2 q0 = LO2(z[0]), q1 = HI2(z[0]), q2 = LO2(z[1]), q3 = HI2(z[1]);
      tanh_pair(q0, q1);
      tanh_pair(q2, q3);
      if (fixw) q0[0] = 1.0f;
      uintx4 hu1 = write_tile(buf1, wrow, T0, quad, q0, q1, q2, q3);
      acc[0] = splat4(0.0f);
      acc[1] = splat4(0.0f);
      gemm_own(a2r[0][0], a2r[1][0], hu1, acc);  // next-step GEMM1 own-kb
    }
    __syncthreads();
  }

  // ---- out = W3'[dt*H2sum, 1] ----
  {
    f32x2 ha00 = splat2(0.01f) * h2s[0][0];
    f32x2 ha01 = splat2(0.01f) * h2s[0][1];
    f32x2 ha10 = splat2(0.01f) * h2s[1][0];
    f32x2 ha11 = splat2(0.01f) * h2s[1][1];
    if (fixw) ha00[0] = 1.0f;  // bias feature for b3
    write_tile(buf2, wrow, T0, quad, ha00, ha01, ha10, ha11);
  }
  __syncthreads();
  {
    bf16x8 a3[2][4];
#pragma unroll
    for (int t = 0; t < 2; ++t)
      load_afrag(W3, b3, NH, QP1, NH, (T0 + t) * 16 + col, quad, 1.0f, a3[t]);
    f32x4 o[2];
    o[0] = splat4(0.0f);
    o[1] = splat4(0.0f);
    gemm_acc(buf2, rbase, a3, o);
#pragma unroll
    for (int t = 0; t < 2; ++t)
#pragma unroll
      for (int r = 0; r < 4; ++r) {
        int q = (T0 + t) * 16 + quad * 4 + r;
        if (q < QP1) out[(b * QP1 + q) * NC + col] = o[t][r];
      }
  }
}

extern "C" void kernel_launch(void* const* d_in, const int* in_sizes, int n_in,
                              void* d_out, int out_size, void* d_ws,
                              size_t ws_size, hipStream_t stream) {
  const float* series = (const float*)d_in[0];
  const float* rand_error = (const float*)d_in[1];
  const float* W1 = (const float*)d_in[2];
  const float* b1 = (const float*)d_in[3];
  const float* W2 = (const float*)d_in[4];
  const float* b2 = (const float*)d_in[5];
  const float* W3 = (const float*)d_in[6];
  const float* b3 = (const float*)d_in[7];
  float* out = (float*)d_out;

  short* Mt = (short*)d_ws;                             // 128*128*2 = 32768 B
  float* sv = (float*)((char*)d_ws + MT_K * MT_K * 2);  // 128 f32

  hipLaunchKernelGGL(arima_prep, dim3(128), dim3(512), 0, stream, W1, b1, W3,
                     b3, Mt, sv);
  hipLaunchKernelGGL(arima_r22, dim3(NB), dim3(NTHR), 0, stream, series,
                     rand_error, W1, b1, W2, b2, W3, b3, Mt, sv, out);
}

// Round 10
// 240.613 us; speedup vs baseline: 1.1089x; 1.1089x over previous
//
#include <hip/hip_runtime.h>

// ARIMA flow sampling, R23 = R20 structure + C-fold ONLY (own-kb reverted).
// Post-mortem R22: own-kb passed & cut conflicts as predicted (1.32e7 ->
// 1.0e7) but regressed 186->212us with FETCH 3.8->45.6MB / WRITE 6.2->87MB
// per dispatch = ~80MB SCRATCH traffic: pre-barrier accumulation extended
// acc/z live ranges across barriers + rotated frag arrays -> allocator
// spilled (SGPR 48->64 corroborates). Conflicts are non-critical (R19), so
// own-kb had no remaining upside. Abandoned.
// R23 keeps only the register-neutral half: C-fold. C=2*log2e folded into
// bf16 W1/W2/Mt/sv at one-time load/prep -> tanh drops its v_mul:
// -16 VALU/thread/step (~3%). Everything else byte-identical to R20
// (186.3us main, 240.8 total, session best).
// Predicted: FETCH ~3.85MB / WRITE ~6.2MB (scratch gone), BANK_CONFLICT
// ~1.32e7, main 186.3 -> 180-184us, VALUBusy ~55, absmax ~0.0078
// (weight requant <=1 bf16 ulp).
//
// Algebra (z carried C-scaled: z_c = C*z):
//   z_c0 := (C*W1)'[x0,0,1] ; v_c = C*sv - dt*z_c0 ; h = 1-2/(e^zc+1)
//   h2 = tanh_c(C*W2'[h1,1])            (GEMM 1, W2 pre-scaled)
//   z_c += (C*dtM) @ h2 + v_c           (GEMM 2, acc_in = z_c)
//   x_100 = W3'[dt*sum_s h2_s, 1]       (unscaled)
// pi storage: position p = 32w + 8q + 4t + r holds feature
// f(p) = 32*(p>>5) + 16*((p>>2)&1) + 4*((p>>3)&3) + (p&3).

#define NB 1024
#define NQ 96
#define NC 16
#define NH 100
#define QP1 97
#define QP2 98
#define NTHR 256
#define STR 136
#define NSTEPS_ 100
#define MT_K 128  // dtM row stride (bf16)
#define CC 2.885390081777927f  // 2*log2(e)

typedef __attribute__((ext_vector_type(8))) short bf16x8;
typedef __attribute__((ext_vector_type(4))) short shortx4;
typedef __attribute__((ext_vector_type(4))) float f32x4;
typedef __attribute__((ext_vector_type(2))) float f32x2;
typedef __attribute__((ext_vector_type(4))) unsigned uintx4;

#define LO2(v) __builtin_shufflevector(v, v, 0, 1)
#define HI2(v) __builtin_shufflevector(v, v, 2, 3)

__device__ __forceinline__ f32x4 splat4(float f) {
  f32x4 v = f;
  return v;
}

__device__ __forceinline__ f32x2 splat2(float f) {
  f32x2 v = f;
  return v;
}

__device__ __forceinline__ short f2bf_rne(float f) {  // one-time paths only
  unsigned u = __builtin_bit_cast(unsigned, f);
  u = u + 0x7fffu + ((u >> 16) & 1u);
  return (short)(u >> 16);
}

// 2 floats -> packed bf16x2 dword, RNE, single instruction.
__device__ __forceinline__ unsigned cvtpk_bf16(float a, float b) {
  unsigned r;
  asm("v_cvt_pk_bf16_f32 %0, %1, %2" : "=v"(r) : "v"(a), "v"(b));
  return r;
}

// hardware exp2 (v_exp_f32)
#if __has_builtin(__builtin_amdgcn_exp2f)
__device__ __forceinline__ float hexp2(float x) {
  return __builtin_amdgcn_exp2f(x);
}
#else
__device__ __forceinline__ float hexp2(float x) {
  float r;
  asm("v_exp_f32 %0, %1\n\ts_nop 1" : "=v"(r) : "v"(x));
  return r;
}
#endif

// tanh on C-prescaled input: x = C*z -> tanh(z) = 1 - 2*rcp(exp2(x)+1).
// 2 VALU + 2 TRANS; in [-1,1] by construction, exact +-1 saturation.
__device__ __forceinline__ float tanh1c(float x) {
  float t = hexp2(x);
  float r = __builtin_amdgcn_rcpf(t + 1.0f);
  return fmaf(-2.0f, r, 1.0f);
}

__device__ __forceinline__ void tanh_pair(f32x2& p, f32x2& q) {
  p[0] = tanh1c(p[0]);
  p[1] = tanh1c(p[1]);
  q[0] = tanh1c(q[0]);
  q[1] = tanh1c(q[1]);
}

// ---------------- prep: dtM = C * dt * W1x @ W3 (bf16) + s-vec -----------
// grid 128 (= n), block 512 (k = tid&127, jslice = tid>>7); LDS reduce.
// Mt and sv carry the C scale (z-domain is C-scaled in main).
__global__ void __launch_bounds__(512) arima_prep(
    const float* __restrict__ W1, const float* __restrict__ b1,
    const float* __restrict__ W3, const float* __restrict__ b3,
    short* __restrict__ Mt, float* __restrict__ sv) {
  __shared__ float part[4][128];
  __shared__ float pb[128];
  const int n = blockIdx.x;
  const int tid = threadIdx.x;
  const int k = tid & 127, js = tid >> 7;
  float s = 0.0f;
  if (n < NH && k < NH) {
    int j0 = js * 25, j1 = (js == 3) ? QP1 : j0 + 25;
    for (int j = j0; j < j1; ++j)
      s = fmaf(W1[n * QP2 + j], W3[j * NH + k], s);
  }
  part[js][k] = s;
  if (tid < 128)
    pb[tid] = (tid < QP1 && n < NH) ? W1[n * QP2 + tid] * b3[tid] : 0.0f;
  __syncthreads();
  if (js == 0) {
    float tot = part[0][k] + part[1][k] + part[2][k] + part[3][k];
    Mt[n * MT_K + k] = f2bf_rne(0.01f * CC * tot);
  }
  if (tid == 0) {
    float d = 0.0f;
    for (int j = 0; j < 128; ++j) d += pb[j];
    sv[n] = (n < NH) ? 0.01f * CC * (d + b1[n] + W1[n * QP2 + QP1]) : 0.0f;
  }
}

// ---------------- main ----------------
// Weight A-frag from fp32 W, pi-permuted k columns, scaled:
// frag slot (kb,i) holds scale*W[m][kcol], kcol = kb*32+16*(i>>2)+quad*4+(i&3).
__device__ void load_afrag(const float* __restrict__ W,
                           const float* __restrict__ bias, int ws, int mvalid,
                           int KW, int m, int quad, float scale,
                           bf16x8 dst[4]) {
#pragma unroll
  for (int kb = 0; kb < 4; ++kb) {
    bf16x8 v;
#pragma unroll
    for (int i = 0; i < 8; ++i) {
      int kcol = kb * 32 + ((i >> 2) << 4) + quad * 4 + (i & 3);
      float f = 0.0f;
      if (m < mvalid) {
        if (kcol < KW) f = W[m * ws + kcol];
        else if (kcol == KW) f = bias[m];
      }
      v[i] = f2bf_rne(f * scale);
    }
    dst[kb] = v;
  }
}

// acc += A * B(LDS). 2 tiles, K=128 (4 kb). acc carries in (z-update!).
__device__ __forceinline__ void gemm_acc(const short* __restrict__ src,
                                         int rbase, const bf16x8 (&A)[2][4],
                                         f32x4 (&acc)[2]) {
#pragma unroll
  for (int kb = 0; kb < 4; ++kb) {
    bf16x8 bv = *(const bf16x8*)(src + rbase + kb * 32);  // 16B aligned
    acc[0] = __builtin_amdgcn_mfma_f32_16x16x32_bf16(A[0][kb], bv, acc[0], 0, 0, 0);
    acc[1] = __builtin_amdgcn_mfma_f32_16x16x32_bf16(A[1][kb], bv, acc[1], 0, 0, 0);
  }
}

// cvt_pk + ONE b128 store: lane (c,q) of wave w owns contiguous storage
// [32w + 8q .. +7] = [t0r0..t0r3, t1r0..t1r3]. 16B-aligned.
__device__ __forceinline__ void write_tile(short* __restrict__ dst, int wrow,
                                           int T0, int quad, f32x2 a0,
                                           f32x2 a1, f32x2 b0, f32x2 b1) {
  uintx4 u;
  u.x = cvtpk_bf16(a0[0], a0[1]);
  u.y = cvtpk_bf16(a1[0], a1[1]);
  u.z = cvtpk_bf16(b0[0], b0[1]);
  u.w = cvtpk_bf16(b1[0], b1[1]);
  *(uintx4*)(dst + wrow + (T0 >> 1) * 32 + quad * 8) = u;
}

__global__ void __launch_bounds__(NTHR, 4)
arima_r23(const float* __restrict__ series,
          const float* __restrict__ rand_error, const float* __restrict__ W1,
          const float* __restrict__ b1, const float* __restrict__ W2,
          const float* __restrict__ b2, const float* __restrict__ W3,
          const float* __restrict__ b3, const short* __restrict__ Mt,
          const float* __restrict__ sv, float* __restrict__ out) {
  __shared__ __align__(16) short buf1[16 * STR];  // h1 (feat 100 = 1.0)
  __shared__ __align__(16) short buf2[16 * STR];  // x0 / h2 / H2avg

  const int tid = threadIdx.x;
  const int w = tid >> 6, l = tid & 63;
  const int col = l & 15, quad = l >> 4;  // col = channel = data row
  const int b = blockIdx.x;               // WG = one batch
  const int T0 = 2 * w;                   // uniform: wave owns tiles 2w,2w+1
  const int wrow = col * STR;
  const int rbase = wrow + quad * 8;
  const bool fixw = (w == 3 && quad == 1);  // owns feat 100 (storage 104)

  // ---- x0 -> buf2 : feats [x0(97), t0=0, 1, 0...], pi-stored ----
  {
    f32x4 xv[2];
#pragma unroll
    for (int t = 0; t < 2; ++t)
#pragma unroll
      for (int r = 0; r < 4; ++r) {
        int q = (T0 + t) * 16 + quad * 4 + r;
        float f = 0.0f;
        if (q < NQ) f = series[(b * NQ + q) * NC + col];
        else if (q == NQ) f = rand_error[b * NC + col];
        else if (q == QP2) f = 1.0f;  // bias feature (q==97: t0 = 0)
        xv[t][r] = f;
      }
    write_tile(buf2, wrow, T0, quad, LO2(xv[0]), HI2(xv[0]), LO2(xv[1]),
               HI2(xv[1]));
  }
  __syncthreads();

  // ---- z_c0 = (C*W1)'[x0,0,1] ; v_c = C*sv - dt*z_c0 ; h1_0 -> buf1 ----
  f32x4 z[2], v[2];
  {
    bf16x8 a1[2][4];  // transient
#pragma unroll
    for (int t = 0; t < 2; ++t)
      load_afrag(W1, b1, QP2, NH, QP2, (T0 + t) * 16 + col, quad, CC, a1[t]);
    z[0] = splat4(0.0f);
    z[1] = splat4(0.0f);
    gemm_acc(buf2, rbase, a1, z);
#pragma unroll
    for (int t = 0; t < 2; ++t) {
      f32x4 s;
#pragma unroll
      for (int r = 0; r < 4; ++r) s[r] = sv[(T0 + t) * 16 + quad * 4 + r];
      v[t] = s - splat4(0.01f) * z[t];
    }
  }
  {
    f32x2 p0 = LO2(z[0]), p1 = HI2(z[0]), p2 = LO2(z[1]), p3 = HI2(z[1]);
    tanh_pair(p0, p1);
    tanh_pair(p2, p3);
    if (fixw) p0[0] = 1.0f;  // h1 feat 100 = 1.0 (W2 bias input)
    write_tile(buf1, wrow, T0, quad, p0, p1, p2, p3);
  }
  __syncthreads();

  // ---- persistent frags: C*W2' + C*dtM (pi-permuted k gather) ----
  bf16x8 a2[2][4], am[2][4];
#pragma unroll
  for (int t = 0; t < 2; ++t) {
    load_afrag(W2, b2, NH, NH, NH, (T0 + t) * 16 + col, quad, CC, a2[t]);
    const short* mrow = Mt + ((T0 + t) * 16 + col) * MT_K;
#pragma unroll
    for (int kb = 0; kb < 4; ++kb) {
      shortx4 lo = *(const shortx4*)(mrow + kb * 32 + quad * 4);
      shortx4 hi = *(const shortx4*)(mrow + kb * 32 + 16 + quad * 4);
      bf16x8 vv;
      vv[0] = lo[0]; vv[1] = lo[1]; vv[2] = lo[2]; vv[3] = lo[3];
      vv[4] = hi[0]; vv[5] = hi[1]; vv[6] = hi[2]; vv[7] = hi[3];
      am[t][kb] = vv;
    }
  }
  f32x2 h2s[2][2];
  h2s[0][0] = splat2(0.0f);
  h2s[0][1] = splat2(0.0f);
  h2s[1][0] = splat2(0.0f);
  h2s[1][1] = splat2(0.0f);

#pragma unroll 1
  for (int step = 0; step < NSTEPS_; ++step) {
    // GEMM 1: h2 = tanh_c(C W2'[h1,1]); store, then accumulate H2sum.
    f32x4 acc[2];
    acc[0] = splat4(0.0f);
    acc[1] = splat4(0.0f);
    gemm_acc(buf1, rbase, a2, acc);
    {
      f32x2 p0 = LO2(acc[0]), p1 = HI2(acc[0]), p2 = LO2(acc[1]),
            p3 = HI2(acc[1]);
      tanh_pair(p0, p1);
      tanh_pair(p2, p3);
      write_tile(buf2, wrow, T0, quad, p0, p1, p2, p3);
      h2s[0][0] = h2s[0][0] + p0;
      h2s[0][1] = h2s[0][1] + p1;
      h2s[1][0] = h2s[1][0] + p2;
      h2s[1][1] = h2s[1][1] + p3;
    }
    __syncthreads();
    // GEMM 2: z_c += (C dtM) h2 (acc_in = z!), z_c += v_c ; h1' -> buf1
    gemm_acc(buf2, rbase, am, z);
    {
      z[0] = z[0] + v[0];
      z[1] = z[1] + v[1];
      f32x2 q0 = LO2(z[0]), q1 = HI2(z[0]), q2 = LO2(z[1]), q3 = HI2(z[1]);
      tanh_pair(q0, q1);
      tanh_pair(q2, q3);
      if (fixw) q0[0] = 1.0f;
      write_tile(buf1, wrow, T0, quad, q0, q1, q2, q3);
    }
    __syncthreads();
  }

  // ---- out = W3'[dt*H2sum, 1] ----
  {
    f32x2 ha00 = splat2(0.01f) * h2s[0][0];
    f32x2 ha01 = splat2(0.01f) * h2s[0][1];
    f32x2 ha10 = splat2(0.01f) * h2s[1][0];
    f32x2 ha11 = splat2(0.01f) * h2s[1][1];
    if (fixw) ha00[0] = 1.0f;  // bias feature for b3
    write_tile(buf2, wrow, T0, quad, ha00, ha01, ha10, ha11);
  }
  __syncthreads();
  {
    bf16x8 a3[2][4];
#pragma unroll
    for (int t = 0; t < 2; ++t)
      load_afrag(W3, b3, NH, QP1, NH, (T0 + t) * 16 + col, quad, 1.0f, a3[t]);
    f32x4 o[2];
    o[0] = splat4(0.0f);
    o[1] = splat4(0.0f);
    gemm_acc(buf2, rbase, a3, o);
#pragma unroll
    for (int t = 0; t < 2; ++t)
#pragma unroll
      for (int r = 0; r < 4; ++r) {
        int q = (T0 + t) * 16 + quad * 4 + r;
        if (q < QP1) out[(b * QP1 + q) * NC + col] = o[t][r];
      }
  }
}

extern "C" void kernel_launch(void* const* d_in, const int* in_sizes, int n_in,
                              void* d_out, int out_size, void* d_ws,
                              size_t ws_size, hipStream_t stream) {
  const float* series = (const float*)d_in[0];
  const float* rand_error = (const float*)d_in[1];
  const float* W1 = (const float*)d_in[2];
  const float* b1 = (const float*)d_in[3];
  const float* W2 = (const float*)d_in[4];
  const float* b2 = (const float*)d_in[5];
  const float* W3 = (const float*)d_in[6];
  const float* b3 = (const float*)d_in[7];
  float* out = (float*)d_out;

  short* Mt = (short*)d_ws;                             // 128*128*2 = 32768 B
  float* sv = (float*)((char*)d_ws + MT_K * MT_K * 2);  // 128 f32

  hipLaunchKernelGGL(arima_prep, dim3(128), dim3(512), 0, stream, W1, b1, W3,
                     b3, Mt, sv);
  hipLaunchKernelGGL(arima_r23, dim3(NB), dim3(NTHR), 0, stream, series,
                     rand_error, W1, b1, W2, b2, W3, b3, Mt, sv, out);
}